// Round 3
// baseline (597.494 us; speedup 1.0000x reference)
//
#include <hip/hip_runtime.h>

// out[n,o] = sum_h silu(sum_w x[n,w]*W1[o,h,w] + b1[o,h]) * W2[o,h] + b2[o]
//   x: [131072, 64] f32, W1: [32,128,64] f32, b1: [32,128], W2: [32,128], b2: [32]
//
// R3 design: barrier-free. W1 (512 KB bf16, L2-resident) is read per-wave directly
// from global into registers with a 1-deep prefetch pipeline; no LDS, no syncthreads.
// MFMA operands swapped (A=W1 h-rows, B=x rows) so the layer-2 h-reduction is
// 3 adds + 2 shfl_xor. Constant folding: W1'=-log2e*W1, b1'=-log2e*b1, w2'=-ln2*w2
// so MFMA emits m=-z*log2e and silu(z)*w2 = m*rcp(1+exp2(m))*w2'.
#define NC    131072
#define WDIM  64
#define ODIM  32
#define HDIM  128
#define LOG2E 1.4426950408889634f
#define LN2   0.6931471805599453f

typedef __attribute__((ext_vector_type(8))) short bf16x8;   // MFMA A/B frag (4 VGPRs)
typedef __attribute__((ext_vector_type(4))) float f32x4;    // MFMA C/D frag
typedef __attribute__((ext_vector_type(4))) float flt4;

__device__ __forceinline__ short f2bf(float f) {
    union { float f; unsigned u; } v; v.f = f;
    unsigned r = (v.u + 0x7FFFu + ((v.u >> 16) & 1u)) >> 16;   // RNE
    return (short)r;
}

// ---------------- prep: W1 -> frag-major bf16 (scaled); b1,w2 -> scaled f32 copies ----
// w1f element (o, frag=t*2+k2, lane, i) = -log2e * W1[o][t*16+(lane&15)][k2*32+(lane>>4)*8+i]
// (A-operand layout for mfma(A=W1,B=x): row h = lane&15, k = (lane>>4)*8+i)
__global__ void prep_kernel(const float* __restrict__ W1, const float* __restrict__ b1,
                            const float* __restrict__ w2, short* __restrict__ w1f,
                            float* __restrict__ b1s, float* __restrict__ w2s) {
    if (blockIdx.x < 128) {
        int tid  = blockIdx.x * 256 + threadIdx.x;   // 32768 threads
        int lane = tid & 63;
        int frag = (tid >> 6) & 15;
        int o    = tid >> 10;
        int t    = frag >> 1;
        int k2   = frag & 1;
        const float* src = W1 + ((size_t)(o * HDIM + t * 16 + (lane & 15)) * WDIM
                                 + k2 * 32 + (lane >> 4) * 8);
        bf16x8 v;
        #pragma unroll
        for (int i = 0; i < 8; ++i) v[i] = f2bf(src[i] * -LOG2E);
        *reinterpret_cast<bf16x8*>(w1f + (size_t)tid * 8) = v;
    } else if (blockIdx.x < 144) {
        int idx = (blockIdx.x - 128) * 256 + threadIdx.x;    // 4096 = O*H
        b1s[idx] = b1[idx] * -LOG2E;
    } else {
        int idx = (blockIdx.x - 144) * 256 + threadIdx.x;
        w2s[idx] = w2[idx] * -LN2;
    }
}

// ---------------- main: 1 wave per workgroup, 32 rows per wave, barrier-free ---------
__global__ __launch_bounds__(64, 6)
void swr_main(const float* __restrict__ x, const short* __restrict__ w1f,
              const float* __restrict__ b1s, const float* __restrict__ w2s,
              const float* __restrict__ b2, float* __restrict__ out)
{
    const int lane = threadIdx.x & 63;
    const int col  = lane & 15;
    const int kq   = lane >> 4;
    const size_t rowbase = (size_t)blockIdx.x * 32;

    // x fragments (B operand: col = x-row, k = kq*8+i), kept in regs for all 32 o's
    bf16x8 xf[2][2];
    #pragma unroll
    for (int s = 0; s < 2; ++s) {
        #pragma unroll
        for (int k2 = 0; k2 < 2; ++k2) {
            const float* p = x + (rowbase + s * 16 + col) * WDIM + k2 * 32 + kq * 8;
            flt4 lo = *reinterpret_cast<const flt4*>(p);
            flt4 hi = *reinterpret_cast<const flt4*>(p + 4);
            bf16x8 a;
            a[0] = f2bf(lo[0]); a[1] = f2bf(lo[1]); a[2] = f2bf(lo[2]); a[3] = f2bf(lo[3]);
            a[4] = f2bf(hi[0]); a[5] = f2bf(hi[1]); a[6] = f2bf(hi[2]); a[7] = f2bf(hi[3]);
            xf[s][k2] = a;
        }
    }

    const bf16x8* wfv = reinterpret_cast<const bf16x8*>(w1f);  // [(o*16+t*2+k2)*64 + lane]
    const flt4*  b1v  = reinterpret_cast<const flt4*>(b1s);    // [o*32 + t*4 + kq]
    const flt4*  w2v  = reinterpret_cast<const flt4*>(w2s);

    // 1-deep prefetch pipeline over the flat (o,t) iteration space
    bf16x8 f0 = wfv[lane];            // o=0, t=0, k2=0
    bf16x8 f1 = wfv[64 + lane];       // o=0, t=0, k2=1
    flt4  b1c = b1v[kq];
    flt4  w2c = w2v[kq];

    #pragma unroll 1
    for (int o = 0; o < ODIM; ++o) {
        const float b2o = b2[o];
        float part[2][4];
        #pragma unroll
        for (int s = 0; s < 2; ++s)
            #pragma unroll
            for (int r = 0; r < 4; ++r) part[s][r] = 0.f;

        #pragma unroll
        for (int t = 0; t < 8; ++t) {
            int ni = o * 8 + t + 1;               // next flat iteration (clamped)
            if (ni > 255) ni = 255;
            int fo = ni >> 3, ft = ni & 7;
            int fb = (fo * 16 + ft * 2) * 64;
            bf16x8 f0n = wfv[fb + lane];
            bf16x8 f1n = wfv[fb + 64 + lane];
            flt4  b1n  = b1v[fo * 32 + ft * 4 + kq];
            flt4  w2n  = w2v[fo * 32 + ft * 4 + kq];

            #pragma unroll
            for (int s = 0; s < 2; ++s) {
                f32x4 acc = { b1c[0], b1c[1], b1c[2], b1c[3] };   // b1 folded into acc
                acc = __builtin_amdgcn_mfma_f32_16x16x32_bf16(f0, xf[s][0], acc, 0, 0, 0);
                acc = __builtin_amdgcn_mfma_f32_16x16x32_bf16(f1, xf[s][1], acc, 0, 0, 0);
                // D: col(lane&15)=x-row, row(kq*4+r)=h within tile -> h = t*16+kq*4+r
                #pragma unroll
                for (int r = 0; r < 4; ++r) {
                    float m  = acc[r];                              // -z*log2e
                    float e  = __builtin_amdgcn_exp2f(m);           // exp(-z)
                    float sg = __builtin_amdgcn_rcpf(1.0f + e);     // sigmoid(z)
                    part[s][r] = __builtin_fmaf(m * sg, w2c[r], part[s][r]);
                }
            }
            f0 = f0n; f1 = f1n; b1c = b1n; w2c = w2n;
        }

        // reduce: 4 h's per lane (adds), then 4 kq groups (2 shfl_xor); store 16 rows/stripe
        #pragma unroll
        for (int s = 0; s < 2; ++s) {
            float u = (part[s][0] + part[s][1]) + (part[s][2] + part[s][3]);
            u += __shfl_xor(u, 16);
            u += __shfl_xor(u, 32);
            if (lane < 16)
                out[(rowbase + s * 16 + lane) * ODIM + o] = u + b2o;
        }
    }
}

extern "C" void kernel_launch(void* const* d_in, const int* in_sizes, int n_in,
                              void* d_out, int out_size, void* d_ws, size_t ws_size,
                              hipStream_t stream)
{
    const float* x  = (const float*)d_in[0];
    const float* W1 = (const float*)d_in[1];
    const float* b1 = (const float*)d_in[2];
    const float* w2 = (const float*)d_in[3];
    const float* b2 = (const float*)d_in[4];
    float* out = (float*)d_out;
    short* w1f = (short*)d_ws;                               // 512 KB
    float* b1s = (float*)((char*)d_ws + 512 * 1024);         // 16 KB
    float* w2s = (float*)((char*)d_ws + 528 * 1024);         // 16 KB

    hipLaunchKernelGGL(prep_kernel, dim3(160), dim3(256), 0, stream,
                       W1, b1, w2, w1f, b1s, w2s);
    hipLaunchKernelGGL(swr_main, dim3(NC / 32), dim3(64), 0, stream,
                       x, w1f, b1s, w2s, b2, out);
}

// Round 4
// 220.992 us; speedup vs baseline: 2.7037x; 2.7037x over previous
//
#include <hip/hip_runtime.h>

// out[n,o] = sum_h silu(sum_w x[n,w]*W1[o,h,w] + b1[o,h]) * W2[o,h] + b2[o]
//   x: [131072, 64] f32, W1: [32,128,64] f32, b1: [32,128], W2: [32,128], b2: [32]
//
// R4: R2's LDS-staged double-buffer (FETCH 18 MB, proven) + R3's swapped-operand
// compute (A=W1 h-rows, B=x rows; validated): b1 flt4 used directly as MFMA C-in,
// layer-2 h-reduce = 3 adds + 2 shfl_xor. Packed-f32 (float2 -> v_pk_*) epilogue.
// Folding: W1'=-log2e*W1, b1'=-log2e*b1, w2'=-ln2*w2 so MFMA emits m=-z*log2e and
// silu(z)*w2 = m*rcp(1+exp2(m))*w2'.
#define NC    131072
#define WDIM  64
#define ODIM  32
#define HDIM  128
#define LOG2E 1.4426950408889634f
#define LN2   0.6931471805599453f

typedef __attribute__((ext_vector_type(8))) short bf16x8;   // MFMA A/B frag (4 VGPRs)
typedef __attribute__((ext_vector_type(4))) float f32x4;    // MFMA C/D frag
typedef __attribute__((ext_vector_type(4))) float flt4;
typedef __attribute__((ext_vector_type(2))) float f32x2;    // packed-f32 pair

__device__ __forceinline__ short f2bf(float f) {
    union { float f; unsigned u; } v; v.f = f;
    unsigned r = (v.u + 0x7FFFu + ((v.u >> 16) & 1u)) >> 16;   // RNE
    return (short)r;
}

// ---------------- prep: W1 -> frag-major bf16 (scaled); b1,w2 -> scaled f32 copies ----
// w1f element (o, frag=t*2+k2, lane, i) = -log2e * W1[o][t*16+(lane&15)][k2*32+(lane>>4)*8+i]
// (A-operand layout: row h = lane&15, k = (lane>>4)*8+i)
__global__ void prep_kernel(const float* __restrict__ W1, const float* __restrict__ b1,
                            const float* __restrict__ w2, short* __restrict__ w1f,
                            float* __restrict__ b1s, float* __restrict__ w2s) {
    if (blockIdx.x < 128) {
        int tid  = blockIdx.x * 256 + threadIdx.x;   // 32768 threads
        int lane = tid & 63;
        int frag = (tid >> 6) & 15;
        int o    = tid >> 10;
        int t    = frag >> 1;
        int k2   = frag & 1;
        const float* src = W1 + ((size_t)(o * HDIM + t * 16 + (lane & 15)) * WDIM
                                 + k2 * 32 + (lane >> 4) * 8);
        bf16x8 v;
        #pragma unroll
        for (int i = 0; i < 8; ++i) v[i] = f2bf(src[i] * -LOG2E);
        *reinterpret_cast<bf16x8*>(w1f + (size_t)tid * 8) = v;
    } else if (blockIdx.x < 144) {
        int idx = (blockIdx.x - 128) * 256 + threadIdx.x;    // 4096 = O*H
        b1s[idx] = b1[idx] * -LOG2E;
    } else {
        int idx = (blockIdx.x - 144) * 256 + threadIdx.x;
        w2s[idx] = w2[idx] * -LN2;
    }
}

__device__ __forceinline__ void async16(void* lds_dst, const void* g_src) {
    __builtin_amdgcn_global_load_lds(
        (const __attribute__((address_space(1))) unsigned int*)g_src,
        (__attribute__((address_space(3))) unsigned int*)lds_dst,
        16, 0, 0);
}

__global__ __launch_bounds__(256, 4)
void swr_main(const float* __restrict__ x, const short* __restrict__ w1f,
              const float* __restrict__ b1s, const float* __restrict__ w2s,
              const float* __restrict__ b2, float* __restrict__ out)
{
    __shared__ short w1lds[2 * 8192];            // double buffer: 16 KB per o
    const int tid  = threadIdx.x;
    const int lane = tid & 63;
    const int wid  = tid >> 6;
    const int col  = lane & 15;
    const int kq   = lane >> 4;
    const size_t rowbase = (size_t)blockIdx.x * 128 + (size_t)wid * 32;

    // x fragments (B operand: col = x-row, k = kq*8+i), kept in regs for all 32 o's
    bf16x8 xf[2][2];
    #pragma unroll
    for (int s = 0; s < 2; ++s) {
        #pragma unroll
        for (int k2 = 0; k2 < 2; ++k2) {
            const float* p = x + (rowbase + s * 16 + col) * WDIM + k2 * 32 + kq * 8;
            flt4 lo = *reinterpret_cast<const flt4*>(p);
            flt4 hi = *reinterpret_cast<const flt4*>(p + 4);
            bf16x8 a;
            a[0] = f2bf(lo[0]); a[1] = f2bf(lo[1]); a[2] = f2bf(lo[2]); a[3] = f2bf(lo[3]);
            a[4] = f2bf(hi[0]); a[5] = f2bf(hi[1]); a[6] = f2bf(hi[2]); a[7] = f2bf(hi[3]);
            xf[s][k2] = a;
        }
    }

    // stage o=0 into buffer 0 (wave stages frags wid*4..wid*4+3; 1 KB each, linear dest)
    #pragma unroll
    for (int f = 0; f < 4; ++f) {
        int frag = wid * 4 + f;
        async16(&w1lds[frag * 512], w1f + frag * 512 + lane * 8);
    }
    __syncthreads();

    const flt4* b1v = reinterpret_cast<const flt4*>(b1s);    // [o*32 + t*4 + kq]
    const flt4* w2v = reinterpret_cast<const flt4*>(w2s);

    #pragma unroll 1
    for (int o = 0; o < ODIM; ++o) {
        const short* cur = &w1lds[(o & 1) * 8192];
        if (o + 1 < ODIM) {                       // prefetch next o into other buffer
            const short* g = w1f + (size_t)(o + 1) * 8192;
            short* nb = &w1lds[((o + 1) & 1) * 8192];
            #pragma unroll
            for (int f = 0; f < 4; ++f) {
                int frag = wid * 4 + f;
                async16(nb + frag * 512, g + frag * 512 + lane * 8);
            }
        }
        const float b2o = b2[o];

        f32x2 part[2][2];
        #pragma unroll
        for (int s = 0; s < 2; ++s)
            #pragma unroll
            for (int p = 0; p < 2; ++p) part[s][p] = (f32x2){0.f, 0.f};

        #pragma unroll
        for (int t = 0; t < 8; ++t) {
            flt4 b1c = b1v[o * 32 + t * 4 + kq];
            flt4 w2c = w2v[o * 32 + t * 4 + kq];
            bf16x8 f0 = *reinterpret_cast<const bf16x8*>(cur + (t * 2 + 0) * 512 + lane * 8);
            bf16x8 f1 = *reinterpret_cast<const bf16x8*>(cur + (t * 2 + 1) * 512 + lane * 8);
            #pragma unroll
            for (int s = 0; s < 2; ++s) {
                // b1 flt4 directly as C-in (no acc-init movs)
                f32x4 acc = __builtin_amdgcn_mfma_f32_16x16x32_bf16(
                                f0, xf[s][0], (f32x4){b1c[0], b1c[1], b1c[2], b1c[3]}, 0, 0, 0);
                acc = __builtin_amdgcn_mfma_f32_16x16x32_bf16(f1, xf[s][1], acc, 0, 0, 0);
                // D: col(lane&15)=x-row, row(kq*4+r) -> h = t*16+kq*4+r
                #pragma unroll
                for (int p = 0; p < 2; ++p) {
                    f32x2 m  = { acc[2 * p], acc[2 * p + 1] };            // -z*log2e
                    f32x2 wp = { w2c[2 * p], w2c[2 * p + 1] };
                    f32x2 mw = m * wp;                                    // off-chain (ILP)
                    f32x2 e  = { __builtin_amdgcn_exp2f(m.x),
                                 __builtin_amdgcn_exp2f(m.y) };           // exp(-z)
                    f32x2 d  = e + (f32x2){1.f, 1.f};                     // v_pk_add
                    f32x2 sg = { __builtin_amdgcn_rcpf(d.x),
                                 __builtin_amdgcn_rcpf(d.y) };            // sigmoid(z)
                    part[s][p] = __builtin_elementwise_fma(mw, sg, part[s][p]);  // v_pk_fma
                }
            }
        }

        // reduce 4 h's per lane (packed adds), then 4 kq groups (2 shfl_xor)
        #pragma unroll
        for (int s = 0; s < 2; ++s) {
            f32x2 u2 = part[s][0] + part[s][1];
            float u = u2.x + u2.y;
            u += __shfl_xor(u, 16);
            u += __shfl_xor(u, 32);
            if (lane < 16)
                out[(rowbase + s * 16 + lane) * ODIM + o] = u + b2o;
        }
        __syncthreads();   // prefetched buffer complete + cur safe to overwrite
    }
}

extern "C" void kernel_launch(void* const* d_in, const int* in_sizes, int n_in,
                              void* d_out, int out_size, void* d_ws, size_t ws_size,
                              hipStream_t stream)
{
    const float* x  = (const float*)d_in[0];
    const float* W1 = (const float*)d_in[1];
    const float* b1 = (const float*)d_in[2];
    const float* w2 = (const float*)d_in[3];
    const float* b2 = (const float*)d_in[4];
    float* out = (float*)d_out;
    short* w1f = (short*)d_ws;                               // 512 KB
    float* b1s = (float*)((char*)d_ws + 512 * 1024);         // 16 KB
    float* w2s = (float*)((char*)d_ws + 528 * 1024);         // 16 KB

    hipLaunchKernelGGL(prep_kernel, dim3(160), dim3(256), 0, stream,
                       W1, b1, w2, w1f, b1s, w2s);
    hipLaunchKernelGGL(swr_main, dim3(NC / 128), dim3(256), 0, stream,
                       x, w1f, b1s, w2s, b2, out);
}

// Round 7
// 211.337 us; speedup vs baseline: 2.8272x; 1.0457x over previous
//
#include <hip/hip_runtime.h>

// out[n,o] = sum_h silu(sum_w x[n,w]*W1[o,h,w] + b1[o,h]) * W2[o,h] + b2[o]
//   x: [131072, 64] f32, W1: [32,128,64] f32, b1: [32,128], W2: [32,128], b2: [32]
//
// R5 (2nd resubmit; two GPUAcquisitionTimeouts in a row — never measured):
// R4 + barrier-drain elimination. All per-o operands (W1 frags, b1', w2') are
// staged into LDS by global_load_lds issued a full iteration ahead; output stores
// are deferred to the next iteration's top. The t-loop touches only LDS, so the
// implicit vmcnt(0) at each __syncthreads finds an empty queue.
// Folding: W1'=-log2e*W1, b1'=-log2e*b1, w2'=-ln2*w2 so MFMA emits m=-z*log2e and
// silu(z)*w2 = m*rcp(1+exp2(m))*w2'.
#define NC    131072
#define WDIM  64
#define ODIM  32
#define HDIM  128
#define LOG2E 1.4426950408889634f
#define LN2   0.6931471805599453f

typedef __attribute__((ext_vector_type(8))) short bf16x8;   // MFMA A/B frag (4 VGPRs)
typedef __attribute__((ext_vector_type(4))) float f32x4;    // MFMA C/D frag
typedef __attribute__((ext_vector_type(4))) float flt4;
typedef __attribute__((ext_vector_type(2))) float f32x2;    // packed-f32 pair

__device__ __forceinline__ short f2bf(float f) {
    union { float f; unsigned u; } v; v.f = f;
    unsigned r = (v.u + 0x7FFFu + ((v.u >> 16) & 1u)) >> 16;   // RNE
    return (short)r;
}

// ---- prep: W1 -> frag-major bf16 (scaled); b1,w2 -> scaled f32, per-o contiguous ----
// w1f element (o, frag=t*2+k2, lane, i) = -log2e * W1[o][t*16+(lane&15)][k2*32+(lane>>4)*8+i]
// b1w2[o*256 + j]: j<128 -> -log2e*b1[o][j]; j>=128 -> -ln2*w2[o][j-128]
__global__ void prep_kernel(const float* __restrict__ W1, const float* __restrict__ b1,
                            const float* __restrict__ w2, short* __restrict__ w1f,
                            float* __restrict__ b1w2) {
    if (blockIdx.x < 128) {
        int tid  = blockIdx.x * 256 + threadIdx.x;   // 32768 threads
        int lane = tid & 63;
        int frag = (tid >> 6) & 15;
        int o    = tid >> 10;
        int t    = frag >> 1;
        int k2   = frag & 1;
        const float* src = W1 + ((size_t)(o * HDIM + t * 16 + (lane & 15)) * WDIM
                                 + k2 * 32 + (lane >> 4) * 8);
        bf16x8 v;
        #pragma unroll
        for (int i = 0; i < 8; ++i) v[i] = f2bf(src[i] * -LOG2E);
        *reinterpret_cast<bf16x8*>(w1f + (size_t)tid * 8) = v;
    } else {
        int idx = (blockIdx.x - 128) * 256 + threadIdx.x;    // 0..8191
        int o = idx >> 8, j = idx & 255;
        b1w2[idx] = (j < 128) ? b1[o * HDIM + j] * -LOG2E
                              : w2[o * HDIM + (j - 128)] * -LN2;
    }
}

__device__ __forceinline__ void async16(void* lds_dst, const void* g_src) {
    __builtin_amdgcn_global_load_lds(
        (const __attribute__((address_space(1))) unsigned int*)g_src,
        (__attribute__((address_space(3))) unsigned int*)lds_dst,
        16, 0, 0);
}

// LDS buffer layout (shorts): [16 frags x 512][b1' 256][w2' 256] = 8704 shorts = 17 KB
#define BUFSH 8704

__global__ __launch_bounds__(256, 4)
void swr_main(const float* __restrict__ x, const short* __restrict__ w1f,
              const float* __restrict__ b1w2, const float* __restrict__ b2,
              float* __restrict__ out)
{
    __shared__ short w1lds[2 * BUFSH];           // 34 KB: double buffer, 17 KB per o
    const int tid  = threadIdx.x;
    const int lane = tid & 63;
    const int wid  = tid >> 6;
    const int col  = lane & 15;
    const int kq   = lane >> 4;
    const size_t rowbase = (size_t)blockIdx.x * 128 + (size_t)wid * 32;

    // x fragments (B operand: col = x-row, k = kq*8+i), kept in regs for all 32 o's
    bf16x8 xf[2][2];
    #pragma unroll
    for (int s = 0; s < 2; ++s) {
        #pragma unroll
        for (int k2 = 0; k2 < 2; ++k2) {
            const float* p = x + (rowbase + s * 16 + col) * WDIM + k2 * 32 + kq * 8;
            flt4 lo = *reinterpret_cast<const flt4*>(p);
            flt4 hi = *reinterpret_cast<const flt4*>(p + 4);
            bf16x8 a;
            a[0] = f2bf(lo[0]); a[1] = f2bf(lo[1]); a[2] = f2bf(lo[2]); a[3] = f2bf(lo[3]);
            a[4] = f2bf(hi[0]); a[5] = f2bf(hi[1]); a[6] = f2bf(hi[2]); a[7] = f2bf(hi[3]);
            xf[s][k2] = a;
        }
    }

    // stage o=0 into buffer 0 (waves stage frags; wave 0 also stages b1'/w2')
    #pragma unroll
    for (int f = 0; f < 4; ++f) {
        int frag = wid * 4 + f;
        async16(&w1lds[frag * 512], w1f + frag * 512 + lane * 8);
    }
    if (wid == 0)
        async16(&w1lds[8192], b1w2 + lane * 4);
    __syncthreads();

    float* op0 = out + (rowbase + col) * ODIM;        // s=0 row for lanes 0..15
    float* op1 = out + (rowbase + 16 + col) * ODIM;   // s=1 row
    float pu0 = 0.f, pu1 = 0.f;

    #pragma unroll 1
    for (int o = 0; o < ODIM; ++o) {
        const short* cur = &w1lds[(o & 1) * BUFSH];

        // flush previous-o results (issued ~1 full iteration before the next drain)
        if (o > 0 && lane < 16) { op0[o - 1] = pu0; op1[o - 1] = pu1; }

        if (o + 1 < ODIM) {                       // prefetch next o into other buffer
            const short* g = w1f + (size_t)(o + 1) * 8192;
            short* nb = &w1lds[((o + 1) & 1) * BUFSH];
            #pragma unroll
            for (int f = 0; f < 4; ++f) {
                int frag = wid * 4 + f;
                async16(nb + frag * 512, g + frag * 512 + lane * 8);
            }
            if (wid == 0)
                async16(nb + 8192, b1w2 + (size_t)(o + 1) * 256 + lane * 4);
        }
        const float b2o = b2[o];
        const flt4* bwl = reinterpret_cast<const flt4*>(cur + 8192);  // [0..31]=b1', [32..63]=w2'

        f32x2 part[2][2];
        #pragma unroll
        for (int s = 0; s < 2; ++s)
            #pragma unroll
            for (int p = 0; p < 2; ++p) part[s][p] = (f32x2){0.f, 0.f};

        #pragma unroll
        for (int t = 0; t < 8; ++t) {
            flt4 b1c = bwl[t * 4 + kq];                               // broadcast ds_read
            flt4 w2c = bwl[32 + t * 4 + kq];
            bf16x8 f0 = *reinterpret_cast<const bf16x8*>(cur + (t * 2 + 0) * 512 + lane * 8);
            bf16x8 f1 = *reinterpret_cast<const bf16x8*>(cur + (t * 2 + 1) * 512 + lane * 8);
            #pragma unroll
            for (int s = 0; s < 2; ++s) {
                f32x4 acc = __builtin_amdgcn_mfma_f32_16x16x32_bf16(
                                f0, xf[s][0], (f32x4){b1c[0], b1c[1], b1c[2], b1c[3]}, 0, 0, 0);
                acc = __builtin_amdgcn_mfma_f32_16x16x32_bf16(f1, xf[s][1], acc, 0, 0, 0);
                // D: col(lane&15)=x-row, row(kq*4+r) -> h = t*16+kq*4+r
                #pragma unroll
                for (int p = 0; p < 2; ++p) {
                    f32x2 m  = { acc[2 * p], acc[2 * p + 1] };            // -z*log2e
                    f32x2 wp = { w2c[2 * p], w2c[2 * p + 1] };
                    f32x2 mw = m * wp;                                    // off-chain (ILP)
                    f32x2 e  = { __builtin_amdgcn_exp2f(m.x),
                                 __builtin_amdgcn_exp2f(m.y) };           // exp(-z)
                    f32x2 d  = e + (f32x2){1.f, 1.f};                     // v_pk_add
                    f32x2 sg = { __builtin_amdgcn_rcpf(d.x),
                                 __builtin_amdgcn_rcpf(d.y) };            // sigmoid(z)
                    part[s][p] = __builtin_elementwise_fma(mw, sg, part[s][p]);  // v_pk_fma
                }
            }
        }

        // reduce 4 h's per lane (packed adds), then 4 kq groups (2 shfl_xor)
        {
            f32x2 u2 = part[0][0] + part[0][1];
            float u = u2.x + u2.y;
            u += __shfl_xor(u, 16);
            u += __shfl_xor(u, 32);
            pu0 = u + b2o;
        }
        {
            f32x2 u2 = part[1][0] + part[1][1];
            float u = u2.x + u2.y;
            u += __shfl_xor(u, 16);
            u += __shfl_xor(u, 32);
            pu1 = u + b2o;
        }
        __syncthreads();   // staging done + cur safe to overwrite; vmem queue is old
    }
    if (lane < 16) { op0[ODIM - 1] = pu0; op1[ODIM - 1] = pu1; }
}

extern "C" void kernel_launch(void* const* d_in, const int* in_sizes, int n_in,
                              void* d_out, int out_size, void* d_ws, size_t ws_size,
                              hipStream_t stream)
{
    const float* x  = (const float*)d_in[0];
    const float* W1 = (const float*)d_in[1];
    const float* b1 = (const float*)d_in[2];
    const float* w2 = (const float*)d_in[3];
    const float* b2 = (const float*)d_in[4];
    float* out = (float*)d_out;
    short* w1f  = (short*)d_ws;                              // 512 KB
    float* b1w2 = (float*)((char*)d_ws + 512 * 1024);        // 32 KB (32 o x 256 f32)

    hipLaunchKernelGGL(prep_kernel, dim3(160), dim3(256), 0, stream,
                       W1, b1, w2, w1f, b1w2);
    hipLaunchKernelGGL(swr_main, dim3(NC / 128), dim3(256), 0, stream,
                       x, w1f, b1w2, b2, out);
}

// Round 8
// 207.880 us; speedup vs baseline: 2.8742x; 1.0166x over previous
//
#include <hip/hip_runtime.h>

// out[n,o] = sum_h silu(sum_w x[n,w]*W1[o,h,w] + b1[o,h]) * W2[o,h] + b2[o]
//   x: [131072, 64] f32, W1: [32,128,64] f32, b1: [32,128], W2: [32,128], b2: [32]
//
// R8: o-split geometry. Block = 256 rows x 16 o's (oh = blockIdx&1 selects o-half).
// Same grid (1024) and LDS (34 KB) as R5 -> 16 waves/CU, 4 blocks/CU; but each wave
// runs 4 row-stripes -> 8 independent silu chains/phase (2x ILP), each staged frag
// feeds 4 MFMAs, and barrier count halves. R5's validated pieces kept: frag-major
// scaled-bf16 W1 via global_load_lds double-buffer, b1'/w2' staged in LDS, deferred
// output stores, packed-f32 epilogue.
// Folding: W1'=-log2e*W1, b1'=-log2e*b1, w2'=-ln2*w2 so MFMA emits m=-z*log2e and
// silu(z)*w2 = m*rcp(1+exp2(m))*w2'.
#define NC    131072
#define WDIM  64
#define ODIM  32
#define HDIM  128
#define LOG2E 1.4426950408889634f
#define LN2   0.6931471805599453f

typedef __attribute__((ext_vector_type(8))) short bf16x8;   // MFMA A/B frag (4 VGPRs)
typedef __attribute__((ext_vector_type(4))) float f32x4;    // MFMA C/D frag
typedef __attribute__((ext_vector_type(4))) float flt4;
typedef __attribute__((ext_vector_type(2))) float f32x2;    // packed-f32 pair

__device__ __forceinline__ short f2bf(float f) {
    union { float f; unsigned u; } v; v.f = f;
    unsigned r = (v.u + 0x7FFFu + ((v.u >> 16) & 1u)) >> 16;   // RNE
    return (short)r;
}

// ---- prep: W1 -> frag-major bf16 (scaled); b1,w2 -> scaled f32, per-o contiguous ----
// w1f element (o, frag=t*2+k2, lane, i) = -log2e * W1[o][t*16+(lane&15)][k2*32+(lane>>4)*8+i]
// b1w2[o*256 + j]: j<128 -> -log2e*b1[o][j]; j>=128 -> -ln2*w2[o][j-128]
__global__ void prep_kernel(const float* __restrict__ W1, const float* __restrict__ b1,
                            const float* __restrict__ w2, short* __restrict__ w1f,
                            float* __restrict__ b1w2) {
    if (blockIdx.x < 128) {
        int tid  = blockIdx.x * 256 + threadIdx.x;   // 32768 threads
        int lane = tid & 63;
        int frag = (tid >> 6) & 15;
        int o    = tid >> 10;
        int t    = frag >> 1;
        int k2   = frag & 1;
        const float* src = W1 + ((size_t)(o * HDIM + t * 16 + (lane & 15)) * WDIM
                                 + k2 * 32 + (lane >> 4) * 8);
        bf16x8 v;
        #pragma unroll
        for (int i = 0; i < 8; ++i) v[i] = f2bf(src[i] * -LOG2E);
        *reinterpret_cast<bf16x8*>(w1f + (size_t)tid * 8) = v;
    } else {
        int idx = (blockIdx.x - 128) * 256 + threadIdx.x;    // 0..8191
        int o = idx >> 8, j = idx & 255;
        b1w2[idx] = (j < 128) ? b1[o * HDIM + j] * -LOG2E
                              : w2[o * HDIM + (j - 128)] * -LN2;
    }
}

__device__ __forceinline__ void async16(void* lds_dst, const void* g_src) {
    __builtin_amdgcn_global_load_lds(
        (const __attribute__((address_space(1))) unsigned int*)g_src,
        (__attribute__((address_space(3))) unsigned int*)lds_dst,
        16, 0, 0);
}

// LDS buffer layout (shorts): [16 frags x 512][b1' 256][w2' 256] = 8704 shorts = 17 KB
#define BUFSH 8704
#define OHALF 16

__global__ __launch_bounds__(256, 4)
void swr_main(const float* __restrict__ x, const short* __restrict__ w1f,
              const float* __restrict__ b1w2, const float* __restrict__ b2,
              float* __restrict__ out)
{
    __shared__ short w1lds[2 * BUFSH];           // 34 KB: double buffer, 17 KB per o
    const int tid  = threadIdx.x;
    const int lane = tid & 63;
    const int wid  = tid >> 6;
    const int col  = lane & 15;
    const int kq   = lane >> 4;
    const int oh   = blockIdx.x & 1;             // o-half: [oh*16, oh*16+16)
    const int rb   = blockIdx.x >> 1;            // row-block: 256 rows
    const int obase = oh * OHALF;
    const size_t rowbase = (size_t)rb * 256 + (size_t)wid * 64;

    // x fragments (B operand: col = x-row, k = kq*8+i): 4 stripes x 2 k-halves
    bf16x8 xf[4][2];
    #pragma unroll
    for (int s = 0; s < 4; ++s) {
        #pragma unroll
        for (int k2 = 0; k2 < 2; ++k2) {
            const float* p = x + (rowbase + s * 16 + col) * WDIM + k2 * 32 + kq * 8;
            flt4 lo = *reinterpret_cast<const flt4*>(p);
            flt4 hi = *reinterpret_cast<const flt4*>(p + 4);
            bf16x8 a;
            a[0] = f2bf(lo[0]); a[1] = f2bf(lo[1]); a[2] = f2bf(lo[2]); a[3] = f2bf(lo[3]);
            a[4] = f2bf(hi[0]); a[5] = f2bf(hi[1]); a[6] = f2bf(hi[2]); a[7] = f2bf(hi[3]);
            xf[s][k2] = a;
        }
    }

    // stage first o into buffer 0 (waves stage frags; wave 0 also stages b1'/w2')
    #pragma unroll
    for (int f = 0; f < 4; ++f) {
        int frag = wid * 4 + f;
        async16(&w1lds[frag * 512], w1f + (size_t)obase * 8192 + frag * 512 + lane * 8);
    }
    if (wid == 0)
        async16(&w1lds[8192], b1w2 + (size_t)obase * 256 + lane * 4);
    __syncthreads();

    float* op[4];
    #pragma unroll
    for (int s = 0; s < 4; ++s) op[s] = out + (rowbase + s * 16 + col) * ODIM;
    float pu[4] = {0.f, 0.f, 0.f, 0.f};

    #pragma unroll 1
    for (int o = 0; o < OHALF; ++o) {
        const int oabs = obase + o;
        const short* cur = &w1lds[(o & 1) * BUFSH];

        // flush previous-o results (issued ~1 full iteration before the next drain)
        if (o > 0 && lane < 16) {
            #pragma unroll
            for (int s = 0; s < 4; ++s) op[s][oabs - 1] = pu[s];
        }

        if (o + 1 < OHALF) {                      // prefetch next o into other buffer
            const short* g = w1f + (size_t)(oabs + 1) * 8192;
            short* nb = &w1lds[((o + 1) & 1) * BUFSH];
            #pragma unroll
            for (int f = 0; f < 4; ++f) {
                int frag = wid * 4 + f;
                async16(nb + frag * 512, g + frag * 512 + lane * 8);
            }
            if (wid == 0)
                async16(nb + 8192, b1w2 + (size_t)(oabs + 1) * 256 + lane * 4);
        }
        const float b2o = b2[oabs];
        const flt4* bwl = reinterpret_cast<const flt4*>(cur + 8192);  // [0..31]=b1',[32..63]=w2'

        f32x2 part[4][2];
        #pragma unroll
        for (int s = 0; s < 4; ++s)
            #pragma unroll
            for (int p = 0; p < 2; ++p) part[s][p] = (f32x2){0.f, 0.f};

        #pragma unroll
        for (int t = 0; t < 8; ++t) {
            flt4 b1c = bwl[t * 4 + kq];                               // broadcast ds_read
            flt4 w2c = bwl[32 + t * 4 + kq];
            bf16x8 f0 = *reinterpret_cast<const bf16x8*>(cur + (t * 2 + 0) * 512 + lane * 8);
            bf16x8 f1 = *reinterpret_cast<const bf16x8*>(cur + (t * 2 + 1) * 512 + lane * 8);
            #pragma unroll
            for (int s = 0; s < 4; ++s) {
                f32x4 acc = __builtin_amdgcn_mfma_f32_16x16x32_bf16(
                                f0, xf[s][0], (f32x4){b1c[0], b1c[1], b1c[2], b1c[3]}, 0, 0, 0);
                acc = __builtin_amdgcn_mfma_f32_16x16x32_bf16(f1, xf[s][1], acc, 0, 0, 0);
                // D: col(lane&15)=x-row, row(kq*4+r) -> h = t*16+kq*4+r
                #pragma unroll
                for (int p = 0; p < 2; ++p) {
                    f32x2 m  = { acc[2 * p], acc[2 * p + 1] };            // -z*log2e
                    f32x2 wp = { w2c[2 * p], w2c[2 * p + 1] };
                    f32x2 mw = m * wp;                                    // off-chain (ILP)
                    f32x2 e  = { __builtin_amdgcn_exp2f(m.x),
                                 __builtin_amdgcn_exp2f(m.y) };           // exp(-z)
                    f32x2 d  = e + (f32x2){1.f, 1.f};                     // v_pk_add
                    f32x2 sg = { __builtin_amdgcn_rcpf(d.x),
                                 __builtin_amdgcn_rcpf(d.y) };            // sigmoid(z)
                    part[s][p] = __builtin_elementwise_fma(mw, sg, part[s][p]);  // v_pk_fma
                }
            }
        }

        // reduce 4 h's per lane (packed adds), then 4 kq groups (2 shfl_xor)
        #pragma unroll
        for (int s = 0; s < 4; ++s) {
            f32x2 u2 = part[s][0] + part[s][1];
            float u = u2.x + u2.y;
            u += __shfl_xor(u, 16);
            u += __shfl_xor(u, 32);
            pu[s] = u + b2o;
        }
        __syncthreads();   // staging done + cur safe to overwrite; vmem queue is old
    }
    if (lane < 16) {
        #pragma unroll
        for (int s = 0; s < 4; ++s) op[s][obase + OHALF - 1] = pu[s];
    }
}

extern "C" void kernel_launch(void* const* d_in, const int* in_sizes, int n_in,
                              void* d_out, int out_size, void* d_ws, size_t ws_size,
                              hipStream_t stream)
{
    const float* x  = (const float*)d_in[0];
    const float* W1 = (const float*)d_in[1];
    const float* b1 = (const float*)d_in[2];
    const float* w2 = (const float*)d_in[3];
    const float* b2 = (const float*)d_in[4];
    float* out = (float*)d_out;
    short* w1f  = (short*)d_ws;                              // 512 KB
    float* b1w2 = (float*)((char*)d_ws + 512 * 1024);        // 32 KB (32 o x 256 f32)

    hipLaunchKernelGGL(prep_kernel, dim3(160), dim3(256), 0, stream,
                       W1, b1, w2, w1f, b1w2);
    hipLaunchKernelGGL(swr_main, dim3(NC / 128), dim3(256), 0, stream,
                       x, w1f, b1w2, b2, out);
}